// Round 2
// baseline (337.912 us; speedup 1.0000x reference)
//
#include <hip/hip_runtime.h>

// Caser forward, MI355X. B=4096, L=5, D=128, NH=16, NV=4, T=100, FC1=752.
// Strategy: fuse everything; G=4 batch elems per block to amortize W1/Wh
// L2 traffic; final phase = coalesced 1KB-row gathers (HBM/L3-bound).
// Round 1: resubmit (round-0 failure was container infra, no data).

constexpr int Bsz  = 4096;
constexpr int Lq   = 5;
constexpr int Dd   = 128;
constexpr int NHh  = 16;
constexpr int NVv  = 4;
constexpr int Tt   = 100;
constexpr int FC1  = 752;   // 4*128 + 16*15
constexpr int G    = 4;     // batch elems per block
constexpr int NTHR = 256;

__global__ __launch_bounds__(NTHR, 4) void caser_fused(
    const int* __restrict__ seq, const int* __restrict__ user,
    const int* __restrict__ items,
    const float* __restrict__ item_table, const float* __restrict__ user_table,
    const float* __restrict__ Wv, const float* __restrict__ bv,
    const float* __restrict__ Wh, const float* __restrict__ bh,
    const float* __restrict__ W1, const float* __restrict__ b1,
    const float* __restrict__ W2_table, const float* __restrict__ b2_table,
    float* __restrict__ out)
{
    __shared__ float emb[G][Lq * Dd];    // 10240 B (reused as `part` in FC1)
    __shared__ float z[G][FC1];          // 12032 B
    __shared__ float xc[G][2 * Dd];      // 4096 B
    __shared__ int   s_items[G * Tt];    // 1600 B
    __shared__ float s_b2[G * Tt];       // 1600 B
    __shared__ float s_res[G * Tt];      // 1600 B

    const int tid = threadIdx.x;
    const int b0  = blockIdx.x * G;

    // ---- phase 0: item ids + b2 gather (coalesced ids, scattered b2) ----
    for (int idx = tid; idx < G * Tt; idx += NTHR) {
        int it = items[b0 * Tt + idx];
        s_items[idx] = it;
        s_b2[idx]    = b2_table[it];
    }

    // ---- phase 1: emb gather (G*5 rows of 128, coalesced per row) ----
    for (int idx = tid; idx < G * Lq * Dd; idx += NTHR) {
        int gt  = idx >> 7;              // g*L + t
        int d   = idx & (Dd - 1);
        int row = seq[b0 * Lq + gt];
        emb[0][idx] = item_table[row * Dd + d];
    }
    // uemb -> xc[g][128..255]
    for (int idx = tid; idx < G * Dd; idx += NTHR) {
        int g = idx >> 7, d = idx & (Dd - 1);
        xc[g][Dd + d] = user_table[user[b0 + g] * Dd + d];
    }
    __syncthreads();

    // ---- phase 2a: vertical conv -> z[g][0..511] ----
    for (int idx = tid; idx < G * NVv * Dd; idx += NTHR) {
        int g = idx >> 9;
        int v = (idx >> 7) & 3;
        int d = idx & (Dd - 1);
        float acc = bv[v];
        #pragma unroll
        for (int t = 0; t < Lq; ++t)
            acc = fmaf(emb[g][t * Dd + d], Wv[v * Lq + t], acc);
        z[g][v * Dd + d] = acc;
    }

    // ---- phase 2b: horizontal convs -> z[g][512..751] ----
    // thread = (l,t)-group * 16 + f : 15 groups * 16 = 240 threads.
    // Lanes in a 16-group share the emb address (LDS broadcast); each thread
    // reads each Wh value once and applies it to all G batch elems.
    if (tid < 240) {
        int glt = tid >> 4, f = tid & 15;
        int l, t;
        if      (glt < 5)  { l = 1; t = glt; }
        else if (glt < 9)  { l = 2; t = glt - 5; }
        else if (glt < 12) { l = 3; t = glt - 9; }
        else if (glt < 14) { l = 4; t = glt - 12; }
        else               { l = 5; t = 0; }
        const int lout = Lq - l + 1;
        const int zoff = (l == 1) ? 0 : (l == 2) ? 80 : (l == 3) ? 144
                       : (l == 4) ? 192 : 224;
        float acc[G];
        {
            float bias = bh[(l - 1) * NHh + f];
            #pragma unroll
            for (int g = 0; g < G; ++g) acc[g] = bias;
        }
        for (int s = 0; s < l; ++s) {
            const float4* w4 = reinterpret_cast<const float4*>(
                Wh + (((l - 1) * NHh + f) * Lq + s) * Dd);
            const int ebase = (t + s) * Dd;
            #pragma unroll 4
            for (int d4 = 0; d4 < Dd / 4; ++d4) {
                float4 w = w4[d4];
                #pragma unroll
                for (int g = 0; g < G; ++g) {
                    float4 e = *reinterpret_cast<const float4*>(
                        &emb[g][ebase + d4 * 4]);
                    acc[g] = fmaf(e.x, w.x,
                             fmaf(e.y, w.y,
                             fmaf(e.z, w.z,
                             fmaf(e.w, w.w, acc[g]))));
                }
            }
        }
        #pragma unroll
        for (int g = 0; g < G; ++g)
            z[g][NVv * Dd + zoff + f * lout + t] = fmaxf(acc[g], 0.0f);
    }
    __syncthreads();

    // ---- phase 3: FC1  x = relu(z @ W1 + b1) ----
    // thread = (half, j): j = column 0..127, half splits the 752 K-range.
    // part[] aliases emb[] (emb is dead now; 1024 floats needed <= 2560).
    float* part = &emb[0][0];
    {
        int j = tid & (Dd - 1);
        int half = tid >> 7;
        float acc[G] = {0.f, 0.f, 0.f, 0.f};
        const float* w1p = W1 + j;
        int i0 = half * (FC1 / 2);
        for (int i = i0; i < i0 + FC1 / 2; i += 4) {
            float4 zz[G];
            #pragma unroll
            for (int g = 0; g < G; ++g)
                zz[g] = *reinterpret_cast<const float4*>(&z[g][i]);
            float w0 = w1p[(i + 0) * Dd];
            float w1 = w1p[(i + 1) * Dd];
            float w2 = w1p[(i + 2) * Dd];
            float w3 = w1p[(i + 3) * Dd];
            #pragma unroll
            for (int g = 0; g < G; ++g)
                acc[g] = fmaf(zz[g].x, w0,
                         fmaf(zz[g].y, w1,
                         fmaf(zz[g].z, w2,
                         fmaf(zz[g].w, w3, acc[g]))));
        }
        #pragma unroll
        for (int g = 0; g < G; ++g)
            part[(half * G + g) * Dd + j] = acc[g];
    }
    __syncthreads();
    if (tid < Dd) {
        #pragma unroll
        for (int g = 0; g < G; ++g)
            xc[g][tid] = fmaxf(part[g * Dd + tid] + part[(G + g) * Dd + tid]
                               + b1[tid], 0.0f);
    }
    __syncthreads();

    // ---- phase 4: res[b][t] = dot(W2_table[item], xc[b]) + b2 ----
    // wave g owns batch elem g: 64 lanes * float4 = one full 1KB row/load.
    {
        const int g    = tid >> 6;
        const int lane = tid & 63;
        const float4 xf = reinterpret_cast<const float4*>(&xc[g][0])[lane];
        #pragma unroll 4
        for (int t = 0; t < Tt; ++t) {
            const float4* wp = reinterpret_cast<const float4*>(
                W2_table + s_items[g * Tt + t] * (2 * Dd));
            float4 w = wp[lane];
            float v = fmaf(w.x, xf.x,
                      fmaf(w.y, xf.y,
                      fmaf(w.z, xf.z, w.w * xf.w)));
            #pragma unroll
            for (int off = 32; off; off >>= 1)
                v += __shfl_xor(v, off);
            if (lane == 0) s_res[g * Tt + t] = v + s_b2[g * Tt + t];
        }
    }
    __syncthreads();
    for (int idx = tid; idx < G * Tt; idx += NTHR)
        out[b0 * Tt + idx] = s_res[idx];
}

extern "C" void kernel_launch(void* const* d_in, const int* in_sizes, int n_in,
                              void* d_out, int out_size, void* d_ws, size_t ws_size,
                              hipStream_t stream) {
    const int*   seq        = (const int*)  d_in[0];
    const int*   user       = (const int*)  d_in[1];
    const int*   items      = (const int*)  d_in[2];
    const float* item_table = (const float*)d_in[3];
    const float* user_table = (const float*)d_in[4];
    const float* Wv         = (const float*)d_in[5];
    const float* bv         = (const float*)d_in[6];
    const float* Wh         = (const float*)d_in[7];
    const float* bh         = (const float*)d_in[8];
    const float* W1         = (const float*)d_in[9];
    const float* b1         = (const float*)d_in[10];
    const float* W2_table   = (const float*)d_in[11];
    const float* b2_table   = (const float*)d_in[12];
    float* out = (float*)d_out;

    caser_fused<<<dim3(Bsz / G), dim3(NTHR), 0, stream>>>(
        seq, user, items, item_table, user_table, Wv, bv, Wh, bh,
        W1, b1, W2_table, b2_table, out);
}

// Round 4
// 325.617 us; speedup vs baseline: 1.0378x; 1.0378x over previous
//
#include <hip/hip_runtime.h>

// Caser forward, MI355X. B=4096, L=5, D=128, NH=16, NV=4, T=100, FC1=752.
// Round 2: split fused kernel. R1 data: 166us, HBM 16%, VALU 24%, occ 45%
// -> latency-bound. Kernel A = gather+convs+FC1 -> xc in ws (4MB).
// Kernel B = the B*T=409600 1KB-row gather-dots at 32 waves/CU.
// Round 3: resubmit (round-3 failure was GPU-acquisition infra, no data).

constexpr int Bsz  = 4096;
constexpr int Lq   = 5;
constexpr int Dd   = 128;
constexpr int NHh  = 16;
constexpr int NVv  = 4;
constexpr int Tt   = 100;
constexpr int FC1  = 752;   // 4*128 + 16*15
constexpr int G    = 4;     // batch elems per block (kernel A)
constexpr int NTHR = 256;

// ---------------- Kernel A: emb gather, convs, FC1 -> xc (B x 2D) ----------
__global__ __launch_bounds__(NTHR, 4) void caser_front(
    const int* __restrict__ seq, const int* __restrict__ user,
    const float* __restrict__ item_table, const float* __restrict__ user_table,
    const float* __restrict__ Wv, const float* __restrict__ bv,
    const float* __restrict__ Wh, const float* __restrict__ bh,
    const float* __restrict__ W1, const float* __restrict__ b1,
    float* __restrict__ xc_ws)
{
    __shared__ float emb[G][Lq * Dd];    // 10240 B (reused as `part` in FC1)
    __shared__ float z[G][FC1];          // 12032 B
    __shared__ float xc[G][2 * Dd];      // 4096 B

    const int tid = threadIdx.x;
    const int b0  = blockIdx.x * G;

    // ---- phase 1: emb gather (G*5 rows of 128, coalesced per row) ----
    for (int idx = tid; idx < G * Lq * Dd; idx += NTHR) {
        int gt  = idx >> 7;              // g*L + t
        int d   = idx & (Dd - 1);
        int row = seq[b0 * Lq + gt];
        emb[0][idx] = item_table[row * Dd + d];
    }
    // uemb -> xc[g][128..255]
    for (int idx = tid; idx < G * Dd; idx += NTHR) {
        int g = idx >> 7, d = idx & (Dd - 1);
        xc[g][Dd + d] = user_table[user[b0 + g] * Dd + d];
    }
    __syncthreads();

    // ---- phase 2a: vertical conv -> z[g][0..511] ----
    for (int idx = tid; idx < G * NVv * Dd; idx += NTHR) {
        int g = idx >> 9;
        int v = (idx >> 7) & 3;
        int d = idx & (Dd - 1);
        float acc = bv[v];
        #pragma unroll
        for (int t = 0; t < Lq; ++t)
            acc = fmaf(emb[g][t * Dd + d], Wv[v * Lq + t], acc);
        z[g][v * Dd + d] = acc;
    }

    // ---- phase 2b: horizontal convs -> z[g][512..751] ----
    // thread = (l,t)-group * 16 + f : 15 groups * 16 = 240 threads.
    if (tid < 240) {
        int glt = tid >> 4, f = tid & 15;
        int l, t;
        if      (glt < 5)  { l = 1; t = glt; }
        else if (glt < 9)  { l = 2; t = glt - 5; }
        else if (glt < 12) { l = 3; t = glt - 9; }
        else if (glt < 14) { l = 4; t = glt - 12; }
        else               { l = 5; t = 0; }
        const int lout = Lq - l + 1;
        const int zoff = (l == 1) ? 0 : (l == 2) ? 80 : (l == 3) ? 144
                       : (l == 4) ? 192 : 224;
        float acc[G];
        {
            float bias = bh[(l - 1) * NHh + f];
            #pragma unroll
            for (int g = 0; g < G; ++g) acc[g] = bias;
        }
        for (int s = 0; s < l; ++s) {
            const float4* w4 = reinterpret_cast<const float4*>(
                Wh + (((l - 1) * NHh + f) * Lq + s) * Dd);
            const int ebase = (t + s) * Dd;
            #pragma unroll 4
            for (int d4 = 0; d4 < Dd / 4; ++d4) {
                float4 w = w4[d4];
                #pragma unroll
                for (int g = 0; g < G; ++g) {
                    float4 e = *reinterpret_cast<const float4*>(
                        &emb[g][ebase + d4 * 4]);
                    acc[g] = fmaf(e.x, w.x,
                             fmaf(e.y, w.y,
                             fmaf(e.z, w.z,
                             fmaf(e.w, w.w, acc[g]))));
                }
            }
        }
        #pragma unroll
        for (int g = 0; g < G; ++g)
            z[g][NVv * Dd + zoff + f * lout + t] = fmaxf(acc[g], 0.0f);
    }
    __syncthreads();

    // ---- phase 3: FC1  x = relu(z @ W1 + b1) ----
    float* part = &emb[0][0];            // emb dead; 1024 <= 2560 floats
    {
        int j = tid & (Dd - 1);
        int half = tid >> 7;
        float acc[G] = {0.f, 0.f, 0.f, 0.f};
        const float* w1p = W1 + j;
        int i0 = half * (FC1 / 2);
        for (int i = i0; i < i0 + FC1 / 2; i += 4) {
            float4 zz[G];
            #pragma unroll
            for (int g = 0; g < G; ++g)
                zz[g] = *reinterpret_cast<const float4*>(&z[g][i]);
            float w0 = w1p[(i + 0) * Dd];
            float w1 = w1p[(i + 1) * Dd];
            float w2 = w1p[(i + 2) * Dd];
            float w3 = w1p[(i + 3) * Dd];
            #pragma unroll
            for (int g = 0; g < G; ++g)
                acc[g] = fmaf(zz[g].x, w0,
                         fmaf(zz[g].y, w1,
                         fmaf(zz[g].z, w2,
                         fmaf(zz[g].w, w3, acc[g]))));
        }
        #pragma unroll
        for (int g = 0; g < G; ++g)
            part[(half * G + g) * Dd + j] = acc[g];
    }
    __syncthreads();
    if (tid < Dd) {
        #pragma unroll
        for (int g = 0; g < G; ++g)
            xc[g][tid] = fmaxf(part[g * Dd + tid] + part[(G + g) * Dd + tid]
                               + b1[tid], 0.0f);
    }
    __syncthreads();

    // ---- write xc to workspace, coalesced ----
    for (int idx = tid; idx < G * 2 * Dd; idx += NTHR)
        xc_ws[b0 * 2 * Dd + idx] = xc[0][idx];
}

// ---------------- Kernel B: res[b][t] = dot(W2_table[item], xc[b]) + b2 ----
// One block per b; 4 waves, each owns t = wv + 4k (25 serial items).
// 32 waves/CU target; unroll keeps ~4 row-loads in flight per wave.
__global__ __launch_bounds__(NTHR, 8) void caser_tail(
    const int* __restrict__ items,
    const float* __restrict__ W2_table, const float* __restrict__ b2_table,
    const float* __restrict__ xc_ws, float* __restrict__ out)
{
    __shared__ int   s_items[Tt];
    __shared__ float s_b2[Tt];

    const int b    = blockIdx.x;
    const int tid  = threadIdx.x;
    const int lane = tid & 63;
    const int wv   = tid >> 6;

    if (tid < Tt) {
        int it = items[b * Tt + tid];
        s_items[tid] = it;
        s_b2[tid]    = b2_table[it];
    }
    const float4 xf =
        reinterpret_cast<const float4*>(xc_ws + b * 2 * Dd)[lane];
    __syncthreads();

    #pragma unroll 4
    for (int k = 0; k < Tt / 4; ++k) {
        const int t = wv + k * 4;
        const float4* wp = reinterpret_cast<const float4*>(
            W2_table + (size_t)s_items[t] * (2 * Dd));
        float4 w = wp[lane];
        float v = fmaf(w.x, xf.x,
                  fmaf(w.y, xf.y,
                  fmaf(w.z, xf.z, w.w * xf.w)));
        #pragma unroll
        for (int off = 32; off; off >>= 1)
            v += __shfl_xor(v, off);
        if (lane == 0) out[b * Tt + t] = v + s_b2[t];
    }
}

extern "C" void kernel_launch(void* const* d_in, const int* in_sizes, int n_in,
                              void* d_out, int out_size, void* d_ws, size_t ws_size,
                              hipStream_t stream) {
    const int*   seq        = (const int*)  d_in[0];
    const int*   user       = (const int*)  d_in[1];
    const int*   items      = (const int*)  d_in[2];
    const float* item_table = (const float*)d_in[3];
    const float* user_table = (const float*)d_in[4];
    const float* Wv         = (const float*)d_in[5];
    const float* bv         = (const float*)d_in[6];
    const float* Wh         = (const float*)d_in[7];
    const float* bh         = (const float*)d_in[8];
    const float* W1         = (const float*)d_in[9];
    const float* b1         = (const float*)d_in[10];
    const float* W2_table   = (const float*)d_in[11];
    const float* b2_table   = (const float*)d_in[12];
    float* out   = (float*)d_out;
    float* xc_ws = (float*)d_ws;         // B * 2D floats = 4 MB

    caser_front<<<dim3(Bsz / G), dim3(NTHR), 0, stream>>>(
        seq, user, item_table, user_table, Wv, bv, Wh, bh, W1, b1, xc_ws);
    caser_tail<<<dim3(Bsz), dim3(NTHR), 0, stream>>>(
        items, W2_table, b2_table, xc_ws, out);
}